// Round 1
// baseline (372.177 us; speedup 1.0000x reference)
//
#include <hip/hip_runtime.h>

// CTC batch cost (keras ctc_batch_cost semantics), blank = C-1.
// B=256 blocks (one per batch element), 256 threads (one per DP state s,
// thread 255 also handles s=256). Alpha double-buffered in LDS, one
// __syncthreads per time step. All logsumexp math in log2 domain (native
// v_exp_f32/v_log_f32), final result scaled by ln2.

constexpr int   Tn  = 1024;
constexpr int   Cc  = 128;
constexpr int   Ln  = 128;
constexpr int   Sm  = 257;          // 2L+1
constexpr float NEG  = -1e30f;
constexpr float EPSf = 1e-7f;
constexpr int   PD  = 8;            // prefetch depth (ring, statically indexed)

__global__ __launch_bounds__(256, 1)
void ctc_fwd_kernel(const int*   __restrict__ y_true,
                    const float* __restrict__ y_pred,
                    const int*   __restrict__ in_len,
                    const int*   __restrict__ lab_len,
                    float*       __restrict__ out)
{
    const int b   = blockIdx.x;
    const int tid = threadIdx.x;
    const int il  = in_len[b];
    const int ll  = lab_len[b];

    __shared__ float bufA[Sm + 2];   // [0],[1] = NEG pads so s-1, s-2 never branch
    __shared__ float bufB[Sm + 2];

    const int s = tid;
    int  e;
    bool skip;
    if (s & 1) {
        const int lab = y_true[(size_t)b * Ln + (s >> 1)];
        e = lab;
        const int prev = (s >= 3) ? y_true[(size_t)b * Ln + (s >> 1) - 1] : -1;
        skip = (s >= 3) && (lab != Cc - 1) && (lab != prev);
    } else {
        e = Cc - 1;                  // blank
        skip = false;
    }
    const bool valid  = s   < 2 * ll + 1;
    const bool valid2 = 256 < 2 * ll + 1;   // for s=256 (thread 255's 2nd state)

    // Per-thread gather column is constant over t.
    const float* gp = y_pred + ((size_t)b * Tn) * Cc + e;

    // ---- t = 0 init ----
    {
        const float g0  = gp[0];
        const float lp0 = log2f(g0 + EPSf);
        float a0 = NEG;
        if (s == 0) a0 = lp0;
        if (s == 1) a0 = (ll > 0) ? lp0 : NEG;
        bufA[2 + s] = a0;
        if (tid == 255) bufA[2 + 256] = NEG;
        if (tid == 0) { bufA[0] = bufA[1] = NEG; bufB[0] = bufB[1] = NEG; }
    }
    __syncthreads();

    // ---- prefetch ring: g[i] holds row (t_base + i) of this thread's column ----
    float g[PD];
#pragma unroll
    for (int i = 0; i < PD; ++i)
        g[i] = gp[(size_t)(1 + i) * Cc];

    float* cur = bufA;
    float* nxt = bufB;

    const int steps   = il - 1;                       // updates run t = 1 .. il-1
    const int nchunks = (steps > 0) ? (steps + PD - 1) / PD : 0;
    int t = 1;

    for (int c = 0; c < nchunks; ++c) {
#pragma unroll
        for (int i = 0; i < PD; ++i) {
            const int tt = t + i;
            const float gcur = g[i];
            // issue prefetch for row tt+PD (clamped; OOB-safe)
            int tl = tt + PD; if (tl > Tn - 1) tl = Tn - 1;
            g[i] = gp[(size_t)tl * Cc];

            // thread 255 needs blank prob for s=256: lane 62 of its wave (tid 254, blank col)
            const float gb = __shfl(gcur, 62);

            const bool act = tt < il;                 // block-uniform predicate

            const float lp = log2f(gcur + EPSf);
            const float a1 = cur[2 + s];
            const float a2 = cur[1 + s];
            const float a3 = skip ? cur[s] : NEG;
            const float m  = fmaxf(a1, fmaxf(a2, a3));
            const float sm = exp2f(a1 - m) + exp2f(a2 - m) + exp2f(a3 - m);
            float nv = m + log2f(sm) + lp;
            nv = valid ? nv : NEG;
            nv = act   ? nv : a1;                     // frozen past il (copy-through)
            nxt[2 + s] = nv;

            if (tid == 255) {                         // state s = 256 (always blank)
                const float lpb = log2f(gb + EPSf);
                const float b1  = cur[2 + 256];
                const float b2  = cur[1 + 256];
                const float mm  = fmaxf(b1, b2);
                const float sb  = exp2f(b1 - mm) + exp2f(b2 - mm);
                float nv2 = mm + log2f(sb) + lpb;
                nv2 = valid2 ? nv2 : NEG;
                nv2 = act    ? nv2 : b1;
                nxt[2 + 256] = nv2;
            }
            __syncthreads();
            float* tmp = cur; cur = nxt; nxt = tmp;
        }
        t += PD;
    }

    if (tid == 0) {
        const int end = 2 * ll;
        const float ae = cur[2 + end];
        int pi = end - 1; if (pi < 0) pi = 0;
        float ap = cur[2 + pi];
        if (ll <= 0) ap = NEG;
        const float m  = fmaxf(ae, ap);
        const float l2 = m + log2f(exp2f(ae - m) + exp2f(ap - m));
        out[b] = -0.69314718055994530942f * l2;       // ln2 * log2-domain loglik, negated
    }
}

extern "C" void kernel_launch(void* const* d_in, const int* in_sizes, int n_in,
                              void* d_out, int out_size, void* d_ws, size_t ws_size,
                              hipStream_t stream) {
    const int*   y_true  = (const int*)  d_in[0];
    const float* y_pred  = (const float*)d_in[1];
    const int*   in_len  = (const int*)  d_in[2];
    const int*   lab_len = (const int*)  d_in[3];
    float*       out     = (float*)      d_out;

    const int B = 256;
    ctc_fwd_kernel<<<dim3(B), dim3(256), 0, stream>>>(y_true, y_pred, in_len, lab_len, out);
}

// Round 3
// 105.652 us; speedup vs baseline: 3.5227x; 3.5227x over previous
//
#include <hip/hip_runtime.h>

// CTC batch cost (keras ctc_batch_cost semantics), blank = C-1.
// One wave64 per batch element. Lane L owns states 4L..4L+3; lane 63 also
// owns state 256. Probability-domain DP in DOUBLE precision (no
// transcendentals in the loop; f64's 2^-1022 across-state range covers the
// worst-case ~200-nat spread that broke f32). Exact power-of-2 rescale every
// 16 steps via integer exponent-max reduce (zero rounding error). Only
// cross-lane dependency per step: prev lane's a3 (one __shfl_up).

constexpr int   Tn   = 1024;
constexpr int   Cc   = 128;
constexpr int   Ln   = 128;
constexpr float EPSf = 1e-7f;
constexpr int   PD   = 16;    // prefetch ring depth == steps per rescale chunk

__global__ __launch_bounds__(64, 1)
void ctc_fwd_kernel(const int*   __restrict__ y_true,
                    const float* __restrict__ y_pred,
                    const int*   __restrict__ in_len,
                    const int*   __restrict__ lab_len,
                    float*       __restrict__ out)
{
    const int b  = blockIdx.x;
    const int L  = threadIdx.x;          // 0..63
    const int il = in_len[b];
    const int ll = lab_len[b];
    const int blank = Cc - 1;

    const int* yb   = y_true + (size_t)b * Ln;
    const int  lab1 = yb[2 * L];                       // label for state 4L+1
    const int  lab2 = yb[2 * L + 1];                   // label for state 4L+3
    const int  labp = (L > 0) ? yb[2 * L - 1] : -1;

    const double skm1 = ((L > 0) && (lab1 != blank) && (lab1 != labp)) ? 1.0 : 0.0;
    const double skm3 = ((lab2 != blank) && (lab2 != lab1)) ? 1.0 : 0.0;

    const float* base = y_pred + (size_t)b * Tn * Cc;

    // ---- t = 0 init (prob domain, f64) ----
    double a0 = 0.0, a1v = 0.0, a2v = 0.0, a3v = 0.0, a4v = 0.0;
    if (L == 0) {
        a0  = (double)(base[blank] + EPSf);                     // state 0
        a1v = (ll > 0) ? (double)(base[lab1] + EPSf) : 0.0;     // state 1
    }
    int shift = 0;   // accumulated power-of-2 exponent (exact)

    const int steps = (il > 0) ? (il - 1) : 0;   // updates run t = 1 .. il-1

    // ---- prefetch ring: rows 1..PD of this lane's 3 columns ----
    float gB[PD], g1[PD], g2[PD];
#pragma unroll
    for (int i = 0; i < PD; ++i) {
        int t = 1 + i; if (t > steps && steps > 0) t = steps; if (t > Tn - 1) t = Tn - 1;
        const float* row = base + (size_t)t * Cc;
        gB[i] = row[blank]; g1[i] = row[lab1]; g2[i] = row[lab2];
    }

    const int nfull = steps / PD;
    int t = 1;

    for (int c = 0; c < nfull; ++c) {
#pragma unroll
        for (int i = 0; i < PD; ++i) {
            const float gb = gB[i], gl1 = g1[i], gl2 = g2[i];
            // prefetch row t+i+PD (clamped to <= steps, always in-bounds)
            int tpf = t + i + PD; if (tpf > steps) tpf = steps;
            const float* row = base + (size_t)tpf * Cc;
            gB[i] = row[blank]; g1[i] = row[lab1]; g2[i] = row[lab2];

            double pa3 = __shfl_up(a3v, 1);
            if (L == 0) pa3 = 0.0;

            const double qb = (double)(gb  + EPSf);
            const double q1 = (double)(gl1 + EPSf);
            const double q2 = (double)(gl2 + EPSf);

            const double n0 = (a0 + pa3) * qb;                   // blank 4L
            const double n1 = fma(skm1, pa3, a0 + a1v) * q1;     // label 4L+1
            const double n2 = (a2v + a1v) * qb;                  // blank 4L+2
            const double n3 = fma(skm3, a1v, a3v + a2v) * q2;    // label 4L+3
            const double n4 = (a4v + a3v) * qb;                  // state 256 (lane 63 only matters)
            a0 = n0; a1v = n1; a2v = n2; a3v = n3; a4v = n4;
        }
        t += PD;

        // ---- exact power-of-2 rescale (every PD steps) ----
        double m = fmax(fmax(a0, a1v), fmax(a2v, a3v));
        m = fmax(m, a4v);
        int e = (m > 0.0) ? (((__double2hiint(m) >> 20) & 0x7ff) - 1023) : -100000;
#pragma unroll
        for (int k = 1; k < 64; k <<= 1) {
            const int oe = __shfl_xor(e, k);
            e = (oe > e) ? oe : e;
        }
        // e >= -1023 (state 0 is a strictly positive product, never all-zero)
        const double sc = __hiloint2double((1023 - e) << 20, 0);   // 2^{-e}
        a0 *= sc; a1v *= sc; a2v *= sc; a3v *= sc; a4v *= sc;
        shift += e;
    }

    // ---- remainder (< PD steps), ring already holds the rows ----
#pragma unroll
    for (int i = 0; i < PD; ++i) {
        if (t + i <= steps) {
            const float gb = gB[i], gl1 = g1[i], gl2 = g2[i];

            double pa3 = __shfl_up(a3v, 1);
            if (L == 0) pa3 = 0.0;

            const double qb = (double)(gb  + EPSf);
            const double q1 = (double)(gl1 + EPSf);
            const double q2 = (double)(gl2 + EPSf);

            const double n0 = (a0 + pa3) * qb;
            const double n1 = fma(skm1, pa3, a0 + a1v) * q1;
            const double n2 = (a2v + a1v) * qb;
            const double n3 = fma(skm3, a1v, a3v + a2v) * q2;
            const double n4 = (a4v + a3v) * qb;
            a0 = n0; a1v = n1; a2v = n2; a3v = n3; a4v = n4;
        }
    }

    // ---- readout: loglik = log2(alpha[2ll] + alpha[2ll-1]) + shift, times ln2 ----
    __shared__ double sA[258];
    sA[4 * L + 0] = a0;
    sA[4 * L + 1] = a1v;
    sA[4 * L + 2] = a2v;
    sA[4 * L + 3] = a3v;
    if (L == 63) sA[256] = a4v;
    __syncthreads();

    if (L == 0) {
        const int end = 2 * ll;
        const double ae = sA[end];
        int pi = end - 1; if (pi < 0) pi = 0;
        double ap = sA[pi];
        if (ll <= 0) ap = 0.0;
        const double s  = ae + ap;              // true alpha-sum * 2^{-shift}
        const double lg = log2(s) + (double)shift;
        out[b] = (float)(-0.6931471805599453 * lg);
    }
}

extern "C" void kernel_launch(void* const* d_in, const int* in_sizes, int n_in,
                              void* d_out, int out_size, void* d_ws, size_t ws_size,
                              hipStream_t stream) {
    const int*   y_true  = (const int*)  d_in[0];
    const float* y_pred  = (const float*)d_in[1];
    const int*   in_len  = (const int*)  d_in[2];
    const int*   lab_len = (const int*)  d_in[3];
    float*       out     = (float*)      d_out;

    ctc_fwd_kernel<<<dim3(256), dim3(64), 0, stream>>>(y_true, y_pred, in_len, lab_len, out);
}

// Round 4
// 97.314 us; speedup vs baseline: 3.8245x; 1.0857x over previous
//
#include <hip/hip_runtime.h>

// CTC batch cost (keras ctc_batch_cost semantics), blank = C-1.
// One wave64 per batch element (256 blocks x 64 threads, 1 wave/CU).
// Lane L owns states 4L..4L+3; lane 63 also owns state 256.
// f64 probability-domain DP (no transcendentals in the loop), exact
// power-of-2 rescale every CK=16 steps via DPP exponent-max reduce.
// Global loads double-buffered in registers with sched_barrier(0) fences
// so the compiler cannot sink them to point-of-use (round-3 failure mode:
// VGPR_Count=44 proved the ring never lived in registers).

constexpr int   Tn   = 1024;
constexpr int   Cc   = 128;
constexpr int   Ln   = 128;
constexpr float EPSf = 1e-7f;
constexpr int   CK   = 16;    // steps per chunk == rescale period

__device__ __forceinline__ int dpp_max_i32(int m) {
    int o;
    o = __builtin_amdgcn_update_dpp(0, m, 0x111, 0xf, 0xf, false); m = o > m ? o : m; // row_shr:1
    o = __builtin_amdgcn_update_dpp(0, m, 0x112, 0xf, 0xf, false); m = o > m ? o : m; // row_shr:2
    o = __builtin_amdgcn_update_dpp(0, m, 0x114, 0xf, 0xf, false); m = o > m ? o : m; // row_shr:4
    o = __builtin_amdgcn_update_dpp(0, m, 0x118, 0xf, 0xf, false); m = o > m ? o : m; // row_shr:8
    o = __builtin_amdgcn_update_dpp(0, m, 0x142, 0xf, 0xf, false); m = o > m ? o : m; // row_bcast:15
    o = __builtin_amdgcn_update_dpp(0, m, 0x143, 0xf, 0xf, false); m = o > m ? o : m; // row_bcast:31
    return m;   // lane 63 holds the wave max
}

__global__ __launch_bounds__(64, 1)
void ctc_fwd_kernel(const int*   __restrict__ y_true,
                    const float* __restrict__ y_pred,
                    const int*   __restrict__ in_len,
                    const int*   __restrict__ lab_len,
                    float*       __restrict__ out)
{
    const int b  = blockIdx.x;
    const int L  = threadIdx.x;          // 0..63
    const int il = in_len[b];
    const int ll = lab_len[b];
    const int blank = Cc - 1;

    const int* yb   = y_true + (size_t)b * Ln;
    const int  lab1 = yb[2 * L];                       // label for state 4L+1
    const int  lab2 = yb[2 * L + 1];                   // label for state 4L+3
    const int  labp = (L > 0) ? yb[2 * L - 1] : -1;

    const double skm1 = ((L > 0) && (lab1 != blank) && (lab1 != labp)) ? 1.0 : 0.0;
    const double skm3 = ((lab2 != blank) && (lab2 != lab1)) ? 1.0 : 0.0;

    const float* base = y_pred + (size_t)b * Tn * Cc;
    const int cB = blank, c1 = lab1, c2 = lab2;

    // ---- t = 0 init (prob domain, f64) ----
    double a0 = 0.0, a1v = 0.0, a2v = 0.0, a3v = 0.0, a4v = 0.0;
    if (L == 0) {
        a0  = (double)(base[blank] + EPSf);
        a1v = (ll > 0) ? (double)(base[lab1] + EPSf) : 0.0;
    }
    int shift = 0;

    const int steps = (il > 0) ? (il - 1) : 0;   // updates run t = 1 .. il-1
    const int nfull = steps / CK;

    // Double-buffered register rings (statically indexed via full unroll).
    float gAB[CK], gA1[CK], gA2[CK];
    float gBB[CK], gB1[CK], gB2[CK];

#define LOADCH(GB, G1, G2, tb) do {                                     \
    _Pragma("unroll")                                                   \
    for (int i = 0; i < CK; ++i) {                                      \
        int t_ = (tb) + i; if (t_ > steps) t_ = steps; if (t_ < 1) t_ = 1; \
        const float* rp_ = base + (size_t)t_ * Cc;                      \
        GB[i] = rp_[cB]; G1[i] = rp_[c1]; G2[i] = rp_[c2];              \
    }                                                                   \
} while (0)

#define DPSTEP(gb_, g1_, g2_) do {                                      \
    double pa3_ = __shfl_up(a3v, 1); if (L == 0) pa3_ = 0.0;            \
    const double qb_ = (double)((gb_) + EPSf);                          \
    const double q1_ = (double)((g1_) + EPSf);                          \
    const double q2_ = (double)((g2_) + EPSf);                          \
    const double n0_ = (a0 + pa3_) * qb_;                               \
    const double n1_ = fma(skm1, pa3_, a0 + a1v) * q1_;                 \
    const double n2_ = (a2v + a1v) * qb_;                               \
    const double n3_ = fma(skm3, a1v, a3v + a2v) * q2_;                 \
    const double n4_ = (a4v + a3v) * qb_;                               \
    a0 = n0_; a1v = n1_; a2v = n2_; a3v = n3_; a4v = n4_;               \
} while (0)

#define RESCALE() do {                                                  \
    double m_ = fmax(fmax(a0, a1v), fmax(a2v, a3v)); m_ = fmax(m_, a4v);\
    int be_ = (__double2hiint(m_) >> 20) & 0x7ff;                       \
    be_ = dpp_max_i32(be_);                                             \
    const int emax_ = __builtin_amdgcn_readlane(be_, 63);               \
    const double sc_ = __hiloint2double((2046 - emax_) << 20, 0);       \
    a0 *= sc_; a1v *= sc_; a2v *= sc_; a3v *= sc_; a4v *= sc_;          \
    shift += emax_ - 1023;                                              \
} while (0)

#define DPCHUNK(GB, G1, G2) do {                                        \
    _Pragma("unroll")                                                   \
    for (int i = 0; i < CK; ++i) { DPSTEP(GB[i], G1[i], G2[i]); }       \
    RESCALE();                                                          \
} while (0)

#define DPCHUNK_PRED(GB, G1, G2, tb) do {                               \
    _Pragma("unroll")                                                   \
    for (int i = 0; i < CK; ++i) {                                      \
        if ((tb) + i <= steps) { DPSTEP(GB[i], G1[i], G2[i]); }         \
    }                                                                   \
} while (0)

    // Prologue: chunk 0 -> A
    LOADCH(gAB, gA1, gA2, 1);

    int c = 0;
    while (c + 2 <= nfull) {
        LOADCH(gBB, gB1, gB2, 1 + CK * (c + 1));
        __builtin_amdgcn_sched_barrier(0);
        DPCHUNK(gAB, gA1, gA2);

        LOADCH(gAB, gA1, gA2, 1 + CK * (c + 2));
        __builtin_amdgcn_sched_barrier(0);
        DPCHUNK(gBB, gB1, gB2);
        c += 2;
    }
    if (c < nfull) {               // one more full chunk (in A), then partial in B
        LOADCH(gBB, gB1, gB2, 1 + CK * (c + 1));
        __builtin_amdgcn_sched_barrier(0);
        DPCHUNK(gAB, gA1, gA2);
        DPCHUNK_PRED(gBB, gB1, gB2, 1 + CK * (c + 1));
    } else {                       // partial chunk (in A)
        DPCHUNK_PRED(gAB, gA1, gA2, 1 + CK * c);
    }

    // ---- readout: loglik = log2(alpha[2ll] + alpha[2ll-1]) + shift, times ln2 ----
    __shared__ double sA[258];
    sA[4 * L + 0] = a0;
    sA[4 * L + 1] = a1v;
    sA[4 * L + 2] = a2v;
    sA[4 * L + 3] = a3v;
    if (L == 63) sA[256] = a4v;
    __syncthreads();

    if (L == 0) {
        const int end = 2 * ll;
        const double ae = sA[end];
        int pi = end - 1; if (pi < 0) pi = 0;
        double ap = sA[pi];
        if (ll <= 0) ap = 0.0;
        const double s  = ae + ap;
        const double lg = log2(s) + (double)shift;
        out[b] = (float)(-0.6931471805599453 * lg);
    }

#undef LOADCH
#undef DPSTEP
#undef RESCALE
#undef DPCHUNK
#undef DPCHUNK_PRED
}

extern "C" void kernel_launch(void* const* d_in, const int* in_sizes, int n_in,
                              void* d_out, int out_size, void* d_ws, size_t ws_size,
                              hipStream_t stream) {
    const int*   y_true  = (const int*)  d_in[0];
    const float* y_pred  = (const float*)d_in[1];
    const int*   in_len  = (const int*)  d_in[2];
    const int*   lab_len = (const int*)  d_in[3];
    float*       out     = (float*)      d_out;

    ctc_fwd_kernel<<<dim3(256), dim3(64), 0, stream>>>(y_true, y_pred, in_len, lab_len, out);
}

// Round 5
// 84.579 us; speedup vs baseline: 4.4003x; 1.1506x over previous
//
#include <hip/hip_runtime.h>

// CTC batch cost (keras ctc_batch_cost semantics), blank = C-1.
// One wave64 per batch element (256 blocks x 64 threads, 1 wave/CU).
// Lane L owns states 4L..4L+3; lane 63 also owns state 256.
// f64 probability-domain DP (no transcendentals in the loop), exact
// power-of-2 rescale every CK=8 steps via DPP exponent-max reduce.
// Cross-lane a3 neighbor via DPP wave_shr:1 (VALU pipe, ~3cy) instead of
// ds_bpermute (~120cy) -- removes the DS pipe from the loop-carried chain.
// CK=8 keeps <=48 loads in flight (vmcnt is 6-bit, max 63), so the
// register double-buffer actually works (round-4 failure: 96 in flight).

constexpr int   Tn   = 1024;
constexpr int   Cc   = 128;
constexpr int   Ln   = 128;
constexpr float EPSf = 1e-7f;
constexpr int   CK   = 8;     // steps per chunk == rescale period

__device__ __forceinline__ int dpp_max_i32(int m) {
    int o;
    o = __builtin_amdgcn_update_dpp(0, m, 0x111, 0xf, 0xf, false); m = o > m ? o : m; // row_shr:1
    o = __builtin_amdgcn_update_dpp(0, m, 0x112, 0xf, 0xf, false); m = o > m ? o : m; // row_shr:2
    o = __builtin_amdgcn_update_dpp(0, m, 0x114, 0xf, 0xf, false); m = o > m ? o : m; // row_shr:4
    o = __builtin_amdgcn_update_dpp(0, m, 0x118, 0xf, 0xf, false); m = o > m ? o : m; // row_shr:8
    o = __builtin_amdgcn_update_dpp(0, m, 0x142, 0xf, 0xf, false); m = o > m ? o : m; // row_bcast:15
    o = __builtin_amdgcn_update_dpp(0, m, 0x143, 0xf, 0xf, false); m = o > m ? o : m; // row_bcast:31
    return m;   // lane 63 holds the wave max
}

// lane L gets lane L-1's value; lane 0 gets exact +0.0 (bound_ctrl=1).
__device__ __forceinline__ double dpp_shr1_f64(double x) {
    const int lo = __double2loint(x), hi = __double2hiint(x);
    const int slo = __builtin_amdgcn_update_dpp(0, lo, 0x138, 0xf, 0xf, true); // wave_shr:1
    const int shi = __builtin_amdgcn_update_dpp(0, hi, 0x138, 0xf, 0xf, true);
    return __hiloint2double(shi, slo);
}

__global__ __launch_bounds__(64, 1)
void ctc_fwd_kernel(const int*   __restrict__ y_true,
                    const float* __restrict__ y_pred,
                    const int*   __restrict__ in_len,
                    const int*   __restrict__ lab_len,
                    float*       __restrict__ out)
{
    const int b  = blockIdx.x;
    const int L  = threadIdx.x;          // 0..63
    const int il = in_len[b];
    const int ll = lab_len[b];
    const int blank = Cc - 1;

    const int* yb   = y_true + (size_t)b * Ln;
    const int  lab1 = yb[2 * L];                       // label for state 4L+1
    const int  lab2 = yb[2 * L + 1];                   // label for state 4L+3
    const int  labp = (L > 0) ? yb[2 * L - 1] : -1;

    const double skm1 = ((L > 0) && (lab1 != blank) && (lab1 != labp)) ? 1.0 : 0.0;
    const double skm3 = ((lab2 != blank) && (lab2 != lab1)) ? 1.0 : 0.0;

    const float* base = y_pred + (size_t)b * Tn * Cc;
    const int cB = blank, c1 = lab1, c2 = lab2;

    // ---- t = 0 init (prob domain, f64) ----
    double a0 = 0.0, a1v = 0.0, a2v = 0.0, a3v = 0.0, a4v = 0.0;
    if (L == 0) {
        a0  = (double)(base[blank] + EPSf);
        a1v = (ll > 0) ? (double)(base[lab1] + EPSf) : 0.0;
    }
    int shift = 0;

    const int steps = (il > 0) ? (il - 1) : 0;   // updates run t = 1 .. il-1
    const int nfull = steps / CK;

    // Double-buffered register rings (statically indexed via full unroll).
    float gAB[CK], gA1[CK], gA2[CK];
    float gBB[CK], gB1[CK], gB2[CK];

#define LOADCH(GB, G1, G2, tb) do {                                     \
    _Pragma("unroll")                                                   \
    for (int i = 0; i < CK; ++i) {                                      \
        int t_ = (tb) + i; if (t_ > steps) t_ = steps; if (t_ < 1) t_ = 1; \
        const float* rp_ = base + (size_t)t_ * Cc;                      \
        GB[i] = rp_[cB]; G1[i] = rp_[c1]; G2[i] = rp_[c2];              \
    }                                                                   \
} while (0)

#define DPSTEP(gb_, g1_, g2_) do {                                      \
    const double pa3_ = dpp_shr1_f64(a3v);                              \
    const double qb_ = (double)((gb_) + EPSf);                          \
    const double q1_ = (double)((g1_) + EPSf);                          \
    const double q2_ = (double)((g2_) + EPSf);                          \
    const double n0_ = (a0 + pa3_) * qb_;                               \
    const double n1_ = fma(skm1, pa3_, a0 + a1v) * q1_;                 \
    const double n2_ = (a2v + a1v) * qb_;                               \
    const double n3_ = fma(skm3, a1v, a3v + a2v) * q2_;                 \
    const double n4_ = (a4v + a3v) * qb_;                               \
    a0 = n0_; a1v = n1_; a2v = n2_; a3v = n3_; a4v = n4_;               \
} while (0)

#define RESCALE() do {                                                  \
    double m_ = fmax(fmax(a0, a1v), fmax(a2v, a3v)); m_ = fmax(m_, a4v);\
    int be_ = (__double2hiint(m_) >> 20) & 0x7ff;                       \
    be_ = dpp_max_i32(be_);                                             \
    const int emax_ = __builtin_amdgcn_readlane(be_, 63);               \
    const double sc_ = __hiloint2double((2046 - emax_) << 20, 0);       \
    a0 *= sc_; a1v *= sc_; a2v *= sc_; a3v *= sc_; a4v *= sc_;          \
    shift += emax_ - 1023;                                              \
} while (0)

#define DPCHUNK(GB, G1, G2) do {                                        \
    _Pragma("unroll")                                                   \
    for (int i = 0; i < CK; ++i) { DPSTEP(GB[i], G1[i], G2[i]); }       \
    RESCALE();                                                          \
} while (0)

#define DPCHUNK_PRED(GB, G1, G2, tb) do {                               \
    _Pragma("unroll")                                                   \
    for (int i = 0; i < CK; ++i) {                                      \
        if ((tb) + i <= steps) { DPSTEP(GB[i], G1[i], G2[i]); }         \
    }                                                                   \
} while (0)

    // Prologue: chunk 0 -> A
    LOADCH(gAB, gA1, gA2, 1);

    int c = 0;
    while (c + 2 <= nfull) {
        __builtin_amdgcn_sched_barrier(0);
        LOADCH(gBB, gB1, gB2, 1 + CK * (c + 1));
        __builtin_amdgcn_sched_barrier(0);
        DPCHUNK(gAB, gA1, gA2);

        __builtin_amdgcn_sched_barrier(0);
        LOADCH(gAB, gA1, gA2, 1 + CK * (c + 2));
        __builtin_amdgcn_sched_barrier(0);
        DPCHUNK(gBB, gB1, gB2);
        c += 2;
    }
    if (c < nfull) {               // one more full chunk (in A), then partial in B
        __builtin_amdgcn_sched_barrier(0);
        LOADCH(gBB, gB1, gB2, 1 + CK * (c + 1));
        __builtin_amdgcn_sched_barrier(0);
        DPCHUNK(gAB, gA1, gA2);
        DPCHUNK_PRED(gBB, gB1, gB2, 1 + CK * (c + 1));
    } else {                       // partial chunk (in A)
        DPCHUNK_PRED(gAB, gA1, gA2, 1 + CK * c);
    }

    // ---- readout: loglik = log2(alpha[2ll] + alpha[2ll-1]) + shift, times ln2 ----
    __shared__ double sA[258];
    sA[4 * L + 0] = a0;
    sA[4 * L + 1] = a1v;
    sA[4 * L + 2] = a2v;
    sA[4 * L + 3] = a3v;
    if (L == 63) sA[256] = a4v;
    __syncthreads();

    if (L == 0) {
        const int end = 2 * ll;
        const double ae = sA[end];
        int pi = end - 1; if (pi < 0) pi = 0;
        double ap = sA[pi];
        if (ll <= 0) ap = 0.0;
        const double s  = ae + ap;
        const double lg = log2(s) + (double)shift;
        out[b] = (float)(-0.6931471805599453 * lg);
    }

#undef LOADCH
#undef DPSTEP
#undef RESCALE
#undef DPCHUNK
#undef DPCHUNK_PRED
}

extern "C" void kernel_launch(void* const* d_in, const int* in_sizes, int n_in,
                              void* d_out, int out_size, void* d_ws, size_t ws_size,
                              hipStream_t stream) {
    const int*   y_true  = (const int*)  d_in[0];
    const float* y_pred  = (const float*)d_in[1];
    const int*   in_len  = (const int*)  d_in[2];
    const int*   lab_len = (const int*)  d_in[3];
    float*       out     = (float*)      d_out;

    ctc_fwd_kernel<<<dim3(256), dim3(64), 0, stream>>>(y_true, y_pred, in_len, lab_len, out);
}

// Round 6
// 76.574 us; speedup vs baseline: 4.8604x; 1.1045x over previous
//
#include <hip/hip_runtime.h>

// CTC batch cost (keras ctc_batch_cost semantics), blank = C-1.
// One wave64 per batch element (256 blocks x 64 threads, 1 wave/CU).
// Lane L owns states 4L..4L+3; lane 63 also owns state 256.
// f64 probability-domain DP (no transcendentals in the loop), exact
// power-of-2 rescale every CK=8 steps via DPP exponent-max reduce.
// Loads: inline-asm global_load_dword into a register double-buffer with
// HK-style counted s_waitcnt vmcnt(24) (never 0 in the steady loop).
// Round-5 failure mode fixed: the wave-uniform blank-column load was being
// turned into an out-of-order SMEM s_load, forcing lgkmcnt(0) drains that
// serialized each chunk. Asm VMEM loads cannot be SMEM-ized.

constexpr int   Tn   = 1024;
constexpr int   Cc   = 128;
constexpr int   Ln   = 128;
constexpr float EPSf = 1e-7f;
constexpr int   CK   = 8;     // steps per chunk == rescale period; 3*CK=24 loads/chunk

__device__ __forceinline__ int dpp_max_i32(int m) {
    int o;
    o = __builtin_amdgcn_update_dpp(0, m, 0x111, 0xf, 0xf, false); m = o > m ? o : m; // row_shr:1
    o = __builtin_amdgcn_update_dpp(0, m, 0x112, 0xf, 0xf, false); m = o > m ? o : m; // row_shr:2
    o = __builtin_amdgcn_update_dpp(0, m, 0x114, 0xf, 0xf, false); m = o > m ? o : m; // row_shr:4
    o = __builtin_amdgcn_update_dpp(0, m, 0x118, 0xf, 0xf, false); m = o > m ? o : m; // row_shr:8
    o = __builtin_amdgcn_update_dpp(0, m, 0x142, 0xf, 0xf, false); m = o > m ? o : m; // row_bcast:15
    o = __builtin_amdgcn_update_dpp(0, m, 0x143, 0xf, 0xf, false); m = o > m ? o : m; // row_bcast:31
    return m;   // lane 63 holds the wave max
}

// lane L gets lane L-1's value; lane 0 gets exact +0.0 (bound_ctrl=1).
__device__ __forceinline__ double dpp_shr1_f64(double x) {
    const int lo = __double2loint(x), hi = __double2hiint(x);
    const int slo = __builtin_amdgcn_update_dpp(0, lo, 0x138, 0xf, 0xf, true); // wave_shr:1
    const int shi = __builtin_amdgcn_update_dpp(0, hi, 0x138, 0xf, 0xf, true);
    return __hiloint2double(shi, slo);
}

__global__ __launch_bounds__(64, 1)
void ctc_fwd_kernel(const int*   __restrict__ y_true,
                    const float* __restrict__ y_pred,
                    const int*   __restrict__ in_len,
                    const int*   __restrict__ lab_len,
                    float*       __restrict__ out)
{
    const int b  = blockIdx.x;
    const int L  = threadIdx.x;          // 0..63
    const int il = in_len[b];
    const int ll = lab_len[b];
    const int blank = Cc - 1;

    const int* yb   = y_true + (size_t)b * Ln;
    const int  lab1 = yb[2 * L];                       // label for state 4L+1
    const int  lab2 = yb[2 * L + 1];                   // label for state 4L+3
    const int  labp = (L > 0) ? yb[2 * L - 1] : -1;

    const double skm1 = ((L > 0) && (lab1 != blank) && (lab1 != labp)) ? 1.0 : 0.0;
    const double skm3 = ((lab2 != blank) && (lab2 != lab1)) ? 1.0 : 0.0;

    const float* base = y_pred + (size_t)b * Tn * Cc;
    const int cB = blank, c1 = lab1, c2 = lab2;

    // ---- t = 0 init (prob domain, f64) ----
    double a0 = 0.0, a1v = 0.0, a2v = 0.0, a3v = 0.0, a4v = 0.0;
    if (L == 0) {
        a0  = (double)(base[blank] + EPSf);
        a1v = (ll > 0) ? (double)(base[lab1] + EPSf) : 0.0;
    }
    int shift = 0;

    const int steps = (il > 0) ? (il - 1) : 0;   // updates run t = 1 .. il-1
    const int nfull = steps / CK;

    // Double-buffered register load buffers (statically indexed, asm-pinned).
    float gAB[CK], gA1[CK], gA2[CK];
    float gBB[CK], gB1[CK], gB2[CK];

#define LOADCH_ASM(G, tb) do {                                          \
    _Pragma("unroll")                                                   \
    for (int i = 0; i < CK; ++i) {                                      \
        int t_ = (tb) + i; if (t_ > steps) t_ = steps; if (t_ < 1) t_ = 1; \
        const float* rp_ = base + (size_t)t_ * Cc;                      \
        asm volatile("global_load_dword %0, %1, off"                    \
                     : "=v"(G##B[i]) : "v"(rp_ + cB));                  \
        asm volatile("global_load_dword %0, %1, off"                    \
                     : "=v"(G##1[i]) : "v"(rp_ + c1));                  \
        asm volatile("global_load_dword %0, %1, off"                    \
                     : "=v"(G##2[i]) : "v"(rp_ + c2));                  \
    }                                                                   \
} while (0)

// counted vmcnt wait, fenced on both sides so DP ops cannot cross it
#define WAIT_VM(n) do {                                                 \
    __builtin_amdgcn_sched_barrier(0);                                  \
    asm volatile("s_waitcnt vmcnt(" #n ")");                            \
    __builtin_amdgcn_sched_barrier(0);                                  \
} while (0)

#define DPSTEP(gb_, g1_, g2_) do {                                      \
    const double pa3_ = dpp_shr1_f64(a3v);                              \
    const double qb_ = (double)((gb_) + EPSf);                          \
    const double q1_ = (double)((g1_) + EPSf);                          \
    const double q2_ = (double)((g2_) + EPSf);                          \
    const double n0_ = (a0 + pa3_) * qb_;                               \
    const double n1_ = fma(skm1, pa3_, a0 + a1v) * q1_;                 \
    const double n2_ = (a2v + a1v) * qb_;                               \
    const double n3_ = fma(skm3, a1v, a3v + a2v) * q2_;                 \
    const double n4_ = (a4v + a3v) * qb_;                               \
    a0 = n0_; a1v = n1_; a2v = n2_; a3v = n3_; a4v = n4_;               \
} while (0)

#define RESCALE() do {                                                  \
    double m_ = fmax(fmax(a0, a1v), fmax(a2v, a3v)); m_ = fmax(m_, a4v);\
    int be_ = (__double2hiint(m_) >> 20) & 0x7ff;                       \
    be_ = dpp_max_i32(be_);                                             \
    const int emax_ = __builtin_amdgcn_readlane(be_, 63);               \
    const double sc_ = __hiloint2double((2046 - emax_) << 20, 0);       \
    a0 *= sc_; a1v *= sc_; a2v *= sc_; a3v *= sc_; a4v *= sc_;          \
    shift += emax_ - 1023;                                              \
} while (0)

#define DPCHUNK(GB, G1, G2) do {                                        \
    _Pragma("unroll")                                                   \
    for (int i = 0; i < CK; ++i) { DPSTEP(GB[i], G1[i], G2[i]); }       \
    RESCALE();                                                          \
} while (0)

#define DPCHUNK_PRED(GB, G1, G2, tb) do {                               \
    _Pragma("unroll")                                                   \
    for (int i = 0; i < CK; ++i) {                                      \
        if ((tb) + i <= steps) { DPSTEP(GB[i], G1[i], G2[i]); }         \
    }                                                                   \
} while (0)

    // Prologue: chunk 0 -> A   (24 VMEM outstanding)
    LOADCH_ASM(gA, 1);

    int c = 0;
    while (c + 2 <= nfull) {
        LOADCH_ASM(gB, 1 + CK * (c + 1));   // 48 outstanding
        WAIT_VM(24);                        // A complete, B in flight
        DPCHUNK(gAB, gA1, gA2);

        LOADCH_ASM(gA, 1 + CK * (c + 2));   // 48 outstanding
        WAIT_VM(24);                        // B complete, A' in flight
        DPCHUNK(gBB, gB1, gB2);
        c += 2;
    }
    if (c < nfull) {               // one more full chunk (A), remainder in B
        LOADCH_ASM(gB, 1 + CK * (c + 1));
        WAIT_VM(24);
        DPCHUNK(gAB, gA1, gA2);
        WAIT_VM(0);
        DPCHUNK_PRED(gBB, gB1, gB2, 1 + CK * (c + 1));
    } else {                       // remainder already in A
        WAIT_VM(0);
        DPCHUNK_PRED(gAB, gA1, gA2, 1 + CK * c);
    }

    // ---- readout: loglik = log2(alpha[2ll] + alpha[2ll-1]) + shift, times ln2 ----
    __shared__ double sA[258];
    sA[4 * L + 0] = a0;
    sA[4 * L + 1] = a1v;
    sA[4 * L + 2] = a2v;
    sA[4 * L + 3] = a3v;
    if (L == 63) sA[256] = a4v;
    __syncthreads();

    if (L == 0) {
        const int end = 2 * ll;
        const double ae = sA[end];
        int pi = end - 1; if (pi < 0) pi = 0;
        double ap = sA[pi];
        if (ll <= 0) ap = 0.0;
        const double s  = ae + ap;
        const double lg = log2(s) + (double)shift;
        out[b] = (float)(-0.6931471805599453 * lg);
    }

#undef LOADCH_ASM
#undef WAIT_VM
#undef DPSTEP
#undef RESCALE
#undef DPCHUNK
#undef DPCHUNK_PRED
}

extern "C" void kernel_launch(void* const* d_in, const int* in_sizes, int n_in,
                              void* d_out, int out_size, void* d_ws, size_t ws_size,
                              hipStream_t stream) {
    const int*   y_true  = (const int*)  d_in[0];
    const float* y_pred  = (const float*)d_in[1];
    const int*   in_len  = (const int*)  d_in[2];
    const int*   lab_len = (const int*)  d_in[3];
    float*       out     = (float*)      d_out;

    ctc_fwd_kernel<<<dim3(256), dim3(64), 0, stream>>>(y_true, y_pred, in_len, lab_len, out);
}

// Round 11
// 64.263 us; speedup vs baseline: 5.7915x; 1.1916x over previous
//
#include <hip/hip_runtime.h>

// CTC batch cost (keras ctc_batch_cost semantics), blank = C-1.
// 256 blocks x 128 threads: wave 0 = DP consumer, wave 1 = load producer.
// Lane L owns states 4L..4L+3; lane 63 also owns state 256.
// f64 probability-domain DP (no transcendentals in the loop), exact
// power-of-2 rescale every CK=8 steps via DPP exponent-max reduce.
// Staging: producer wave issues __builtin_amdgcn_global_load_lds into a
// 4-slot LDS ring, 2 chunks ahead, gated by counted s_waitcnt vmcnt(17)
// + raw s_barrier (stage->vmcnt->barrier, the proven 8-phase mechanism).
// In-flight data lives in LDS, not VGPRs: rounds 7-10 proved that inline
// asm loads with live register buffers beyond the r6 envelope corrupt
// execution (allocator reuses pending asm dest/address regs). The only
// asm left is operand-free s_waitcnt in the producer.

constexpr int   Tn    = 1024;
constexpr int   Cc    = 128;
constexpr int   Ln    = 128;
constexpr float EPSf  = 1e-7f;
constexpr int   CK    = 8;     // rows per chunk == rescale period
constexpr int   NSLOT = 4;     // LDS ring slots (2 ahead + 1 read + spare)

__device__ __forceinline__ int dpp_max_i32(int m) {
    int o;
    o = __builtin_amdgcn_update_dpp(0, m, 0x111, 0xf, 0xf, false); m = o > m ? o : m; // row_shr:1
    o = __builtin_amdgcn_update_dpp(0, m, 0x112, 0xf, 0xf, false); m = o > m ? o : m; // row_shr:2
    o = __builtin_amdgcn_update_dpp(0, m, 0x114, 0xf, 0xf, false); m = o > m ? o : m; // row_shr:4
    o = __builtin_amdgcn_update_dpp(0, m, 0x118, 0xf, 0xf, false); m = o > m ? o : m; // row_shr:8
    o = __builtin_amdgcn_update_dpp(0, m, 0x142, 0xf, 0xf, false); m = o > m ? o : m; // row_bcast:15
    o = __builtin_amdgcn_update_dpp(0, m, 0x143, 0xf, 0xf, false); m = o > m ? o : m; // row_bcast:31
    return m;   // lane 63 holds the wave max
}

// lane L gets lane L-1's value; lane 0 gets exact +0.0 (bound_ctrl=1).
__device__ __forceinline__ double dpp_shr1_f64(double x) {
    const int lo = __double2loint(x), hi = __double2hiint(x);
    const int slo = __builtin_amdgcn_update_dpp(0, lo, 0x138, 0xf, 0xf, true); // wave_shr:1
    const int shi = __builtin_amdgcn_update_dpp(0, hi, 0x138, 0xf, 0xf, true);
    return __hiloint2double(shi, slo);
}

__global__ __launch_bounds__(128, 1)
void ctc_fwd_kernel(const int*   __restrict__ y_true,
                    const float* __restrict__ y_pred,
                    const int*   __restrict__ in_len,
                    const int*   __restrict__ lab_len,
                    float*       __restrict__ out)
{
    const int tid = threadIdx.x;
    const int L   = tid & 63;            // lane within wave
    const int b   = blockIdx.x;
    const int il  = in_len[b];
    const int ll  = lab_len[b];
    const int blank = Cc - 1;

    const int* yb   = y_true + (size_t)b * Ln;
    const int  lab1 = yb[2 * L];                       // label for state 4L+1
    const int  lab2 = yb[2 * L + 1];                   // label for state 4L+3

    const float* base = y_pred + (size_t)b * Tn * Cc;
    const int steps = (il > 0) ? (il - 1) : 0;         // updates run t = 1 .. il-1
    const int nfull = steps / CK;
    const int nch   = (steps + CK - 1) / CK;

    __shared__ float  ldsL1[NSLOT][CK][64];
    __shared__ float  ldsL2[NSLOT][CK][64];
    __shared__ float  ldsBK[NSLOT][CK];
    __shared__ double sA[258];

#define BARRIER() do {                                                  \
    __builtin_amdgcn_sched_barrier(0);                                  \
    asm volatile("" ::: "memory");                                      \
    __builtin_amdgcn_s_barrier();                                       \
    asm volatile("" ::: "memory");                                      \
    __builtin_amdgcn_sched_barrier(0);                                  \
} while (0)

#define WAIT_VM(n) do {                                                 \
    __builtin_amdgcn_sched_barrier(0);                                  \
    asm volatile("s_waitcnt vmcnt(" #n ")");                            \
    __builtin_amdgcn_sched_barrier(0);                                  \
} while (0)

    if (tid >= 64) {
        // ---------------- producer wave ----------------
        // 17 VMEM insts per chunk: 1 blank (lanes 0..7 cover the 8 rows),
        // 8 lab1 rows, 8 lab2 rows. LDS dst = wave-uniform base + lane*4.
#define ISSUE_CHUNK(k) do {                                             \
    const int slot_ = (k) & (NSLOT - 1);                                \
    {                                                                   \
        int tb_ = 1 + (k) * CK + L; if (tb_ > steps) tb_ = steps; if (tb_ < 0) tb_ = 0; \
        const float* g_ = base + (size_t)tb_ * Cc + blank;              \
        if (L < CK)                                                     \
            __builtin_amdgcn_global_load_lds(                           \
                (const __attribute__((address_space(1))) void*)g_,      \
                (__attribute__((address_space(3))) void*)&ldsBK[slot_][0], 4, 0, 0); \
    }                                                                   \
    _Pragma("unroll")                                                   \
    for (int r_ = 0; r_ < CK; ++r_) {                                   \
        int t_ = 1 + (k) * CK + r_; if (t_ > steps) t_ = steps; if (t_ < 0) t_ = 0; \
        const float* row_ = base + (size_t)t_ * Cc;                     \
        __builtin_amdgcn_global_load_lds(                               \
            (const __attribute__((address_space(1))) void*)(row_ + lab1), \
            (__attribute__((address_space(3))) void*)&ldsL1[slot_][r_][0], 4, 0, 0); \
        __builtin_amdgcn_global_load_lds(                               \
            (const __attribute__((address_space(1))) void*)(row_ + lab2), \
            (__attribute__((address_space(3))) void*)&ldsL2[slot_][r_][0], 4, 0, 0); \
    }                                                                   \
} while (0)

        ISSUE_CHUNK(0);
        ISSUE_CHUNK(1);
        WAIT_VM(17);                 // chunk 0 complete, chunk 1 in flight
        BARRIER();
        for (int i = 0; i < nch; ++i) {
            if (i + 2 < nch) {
                ISSUE_CHUNK(i + 2);  // <= 34 outstanding
                WAIT_VM(17);         // chunk i+1 complete before barrier
            } else {
                WAIT_VM(0);          // tail: everything landed
            }
            BARRIER();
        }
        return;
#undef ISSUE_CHUNK
    }

    // ---------------- consumer wave (DP) ----------------
    const int  labp = (L > 0) ? yb[2 * L - 1] : -1;
    const double skm1 = ((L > 0) && (lab1 != blank) && (lab1 != labp)) ? 1.0 : 0.0;
    const double skm3 = ((lab2 != blank) && (lab2 != lab1)) ? 1.0 : 0.0;

    double a0 = 0.0, a1v = 0.0, a2v = 0.0, a3v = 0.0, a4v = 0.0;
    if (L == 0) {
        a0  = (double)(base[blank] + EPSf);
        a1v = (ll > 0) ? (double)(base[lab1] + EPSf) : 0.0;
    }
    int shift = 0;

#define DPSTEP(gb_, g1_, g2_) do {                                      \
    const double pa3_ = dpp_shr1_f64(a3v);                              \
    const double qb_ = (double)((gb_) + EPSf);                          \
    const double q1_ = (double)((g1_) + EPSf);                          \
    const double q2_ = (double)((g2_) + EPSf);                          \
    const double n0_ = (a0 + pa3_) * qb_;                               \
    const double n1_ = fma(skm1, pa3_, a0 + a1v) * q1_;                 \
    const double n2_ = (a2v + a1v) * qb_;                               \
    const double n3_ = fma(skm3, a1v, a3v + a2v) * q2_;                 \
    const double n4_ = (a4v + a3v) * qb_;                               \
    a0 = n0_; a1v = n1_; a2v = n2_; a3v = n3_; a4v = n4_;               \
} while (0)

#define RESCALE() do {                                                  \
    double m_ = fmax(fmax(a0, a1v), fmax(a2v, a3v)); m_ = fmax(m_, a4v);\
    int be_ = (__double2hiint(m_) >> 20) & 0x7ff;                       \
    be_ = dpp_max_i32(be_);                                             \
    const int emax_ = __builtin_amdgcn_readlane(be_, 63);               \
    const double sc_ = __hiloint2double((2046 - emax_) << 20, 0);       \
    a0 *= sc_; a1v *= sc_; a2v *= sc_; a3v *= sc_; a4v *= sc_;          \
    shift += emax_ - 1023;                                              \
} while (0)

    BARRIER();                       // matches producer prologue barrier

    for (int i = 0; i < nch; ++i) {
        const int slot = i & (NSLOT - 1);
        if (i < nfull) {
#pragma unroll
            for (int r = 0; r < CK; ++r)
                DPSTEP(ldsBK[slot][r], ldsL1[slot][r][L], ldsL2[slot][r][L]);
        } else {
#pragma unroll
            for (int r = 0; r < CK; ++r) {
                if (1 + i * CK + r <= steps)
                    DPSTEP(ldsBK[slot][r], ldsL1[slot][r][L], ldsL2[slot][r][L]);
            }
        }
        RESCALE();
        BARRIER();
    }

    // ---- readout (single wave; DS ops in-order within the wave) ----
    sA[4 * L + 0] = a0;
    sA[4 * L + 1] = a1v;
    sA[4 * L + 2] = a2v;
    sA[4 * L + 3] = a3v;
    if (L == 63) sA[256] = a4v;

    if (L == 0) {
        const int end = 2 * ll;
        const double ae = sA[end];
        int pi = end - 1; if (pi < 0) pi = 0;
        double ap = sA[pi];
        if (ll <= 0) ap = 0.0;
        const double s  = ae + ap;
        const double lg = log2(s) + (double)shift;
        out[b] = (float)(-0.6931471805599453 * lg);
    }

#undef BARRIER
#undef WAIT_VM
#undef DPSTEP
#undef RESCALE
}

extern "C" void kernel_launch(void* const* d_in, const int* in_sizes, int n_in,
                              void* d_out, int out_size, void* d_ws, size_t ws_size,
                              hipStream_t stream) {
    const int*   y_true  = (const int*)  d_in[0];
    const float* y_pred  = (const float*)d_in[1];
    const int*   in_len  = (const int*)  d_in[2];
    const int*   lab_len = (const int*)  d_in[3];
    float*       out     = (float*)      d_out;

    ctc_fwd_kernel<<<dim3(256), dim3(128), 0, stream>>>(y_true, y_pred, in_len, lab_len, out);
}